// Round 7
// baseline (485.403 us; speedup 1.0000x reference)
//
#include <hip/hip_runtime.h>
#include <cstdint>
#include <cstddef>

// Dtypes PROVEN fp32 (R2 bf16-read -> NaN; R4 fp32-read -> pass, absmax 0.0078).
#define N_NODES 8192
#define FIN 256
#define FOUT 128
#define MT 32                 // rows per block in gat kernel
#define KC 256                // j-chunk size
#define JS 4                  // j slices (partial softmax, merged in gat epilogue)
#define JW (N_NODES / JS)     // 2048 columns per slice
#define NCHS (JW / KC)        // 8 chunks per block
#define LOG2E 1.4426950408889634f

typedef __attribute__((ext_vector_type(8))) short bf16x8;
typedef __attribute__((ext_vector_type(4))) float f32x4;
typedef __attribute__((ext_vector_type(4))) int i32x4;
typedef __attribute__((ext_vector_type(2))) unsigned int u32x2;
typedef __attribute__((ext_vector_type(4))) unsigned int u32x4;

__device__ __forceinline__ float bf2f(unsigned short u) {
    union { unsigned int i; float f; } v; v.i = ((unsigned int)u) << 16; return v.f;
}
__device__ __forceinline__ unsigned short f2bf(float f) {
    union { float f; unsigned int i; } v; v.f = f;
    unsigned int r = (v.i + 0x7FFFu + ((v.i >> 16) & 1u)) >> 16;
    return (unsigned short)r;
}
__device__ __forceinline__ unsigned int pack_bf16(float a, float b) {
    return (unsigned)f2bf(a) | ((unsigned)f2bf(b) << 16);
}

// whB fragment-order layout: tile (kb, fb) holds Wh[j=kb*32+quad*8+e][f=fb*16+sl]
// at element ((kb*8+fb)*512 + (quad*16+sl)*8 + e) -> a wave's B-load is one
// contiguous 1 KB burst.
__device__ __forceinline__ size_t whb_idx(int j, int f) {
    return ((size_t)((j >> 5) * 8 + (f >> 4)) << 9) + (((j >> 3) & 3) << 7)
         + ((f & 15) << 3) + (j & 7);
}

// ---------------- Kernel A: whB = fragment-ordered bf16 (h @ W^T), MFMA -------
// R6 structure (proven -16 us): h staged f32x4-coalesced -> bf16 LDS (stride
// 264, conflict-free b128); W staged in fragment order. s-pass fused (R4):
// per-f0-block partials plain-stored (gat sums them). R7: also zero-inits the
// gat completion counters (block (0,0); ws is re-poisoned each iteration).
__global__ __launch_bounds__(256) void wh_kernel(const float* __restrict__ h,
                                                 const float* __restrict__ W,
                                                 const float* __restrict__ a1,
                                                 const float* __restrict__ a2,
                                                 unsigned short* __restrict__ whB,
                                                 float* __restrict__ s1p,
                                                 float* __restrict__ s2p,
                                                 int* __restrict__ cnt) {
    __shared__ __align__(16) unsigned short hB[64][264];       // 33 KB bf16
    __shared__ __align__(16) unsigned short wLds[16 * 64 * 8]; // 16 KB frag order
    const int t = threadIdx.x;
    const int i0 = blockIdx.x * 64;
    const int f0 = blockIdx.y * 32;
    if (blockIdx.x == 0 && blockIdx.y == 0) cnt[t] = 0;   // 256 counters
    // ---- stage h (64 x 256 f32, fully coalesced) -> bf16 LDS ----
#pragma unroll
    for (int c = 0; c < 8; ++c) {
        int chunk = c * 256 + t;          // 0..2047: 8-col groups
        int row = chunk >> 5;             // 0..63
        int g8  = chunk & 31;             // col group [g8*8, g8*8+8)
        const float* hp = &h[(size_t)(i0 + row) * FIN + g8 * 8];
        f32x4 v0 = *(const f32x4*)hp;
        f32x4 v1 = *(const f32x4*)(hp + 4);
        u32x4 pk;
        pk.x = pack_bf16(v0[0], v0[1]); pk.y = pack_bf16(v0[2], v0[3]);
        pk.z = pack_bf16(v1[0], v1[1]); pk.w = pack_bf16(v1[2], v1[3]);
        *(u32x4*)&hB[row][g8 * 8] = pk;
    }
    // ---- stage W tile (32 f x 256 k) -> bf16 fragment order (R5, proven) ----
    {
        const int kk = t & 7;          // k-tile this thread fills
        const int fr = t >> 3;         // local f row 0..31
        const int fh = fr >> 4;
        const float* wr = W + (size_t)(f0 + fr) * FIN + kk * 32;
#pragma unroll
        for (int g = 0; g < 4; ++g) {  // quad groups
            f32x4 v0 = *(const f32x4*)(wr + g * 8);
            f32x4 v1 = *(const f32x4*)(wr + g * 8 + 4);
            u32x4 pk;
            pk.x = pack_bf16(v0[0], v0[1]); pk.y = pack_bf16(v0[2], v0[3]);
            pk.z = pack_bf16(v1[0], v1[1]); pk.w = pack_bf16(v1[2], v1[3]);
            *(u32x4*)&wLds[(size_t)(((kk * 2 + fh) * 64) + (fr & 15) + g * 16) * 8] = pk;
        }
    }
    __syncthreads();
    const int lane = t & 63;
    const int wv = t >> 6;             // i-stripe: rows i0+wv*16 .. +15
    const int quad = lane >> 4;
    const int sl = lane & 15;
    f32x4 acc0 = {0.f,0.f,0.f,0.f}, acc1 = {0.f,0.f,0.f,0.f};
#pragma unroll
    for (int kk = 0; kk < 8; ++kk) {
        bf16x8 A  = *(const bf16x8*)&hB[wv * 16 + sl][kk * 32 + quad * 8];
        bf16x8 B0 = *(const bf16x8*)&wLds[(size_t)((kk * 2 + 0) * 64 + lane) * 8];
        bf16x8 B1 = *(const bf16x8*)&wLds[(size_t)((kk * 2 + 1) * 64 + lane) * 8];
        acc0 = __builtin_amdgcn_mfma_f32_16x16x32_bf16(A, B0, acc0, 0, 0, 0);
        acc1 = __builtin_amdgcn_mfma_f32_16x16x32_bf16(A, B1, acc1, 0, 0, 0);
    }
    // ---- D layout: i-local = wv*16 + quad*4 + r, f-local = fh*16 + sl ----
    const float a1v0 = a1[f0 + sl], a1v1 = a1[f0 + 16 + sl];
    const float a2v0 = a2[f0 + sl], a2v1 = a2[f0 + 16 + sl];
    float c1[4], c2[4];
#pragma unroll
    for (int r = 0; r < 4; ++r) {
        int i = i0 + wv * 16 + quad * 4 + r;
        whB[whb_idx(i, f0 + sl)]      = f2bf(acc0[r]);
        whB[whb_idx(i, f0 + 16 + sl)] = f2bf(acc1[r]);
        c1[r] = acc0[r] * a1v0 + acc1[r] * a1v1;
        c2[r] = acc0[r] * a2v0 + acc1[r] * a2v1;
    }
    // reduce the 16 sl-lanes (full 32-f partial lives in every quad group)
#pragma unroll
    for (int r = 0; r < 4; ++r) {
        c1[r] += __shfl_xor(c1[r], 1); c2[r] += __shfl_xor(c2[r], 1);
        c1[r] += __shfl_xor(c1[r], 2); c2[r] += __shfl_xor(c2[r], 2);
        c1[r] += __shfl_xor(c1[r], 4); c2[r] += __shfl_xor(c2[r], 4);
        c1[r] += __shfl_xor(c1[r], 8); c2[r] += __shfl_xor(c2[r], 8);
    }
    if (sl == 0) {
#pragma unroll
        for (int r = 0; r < 4; ++r) {
            int i = i0 + wv * 16 + quad * 4 + r;
            s1p[(size_t)blockIdx.y * N_NODES + i] = c1[r] * LOG2E;
            s2p[(size_t)blockIdx.y * N_NODES + i] = c2[r] * LOG2E;
        }
    }
}

// ---------------- Kernel C: fused mask+softmax-partial+PV MFMA + merge --------
// EXACT R4/R6 main-loop (champion). grid 1024 (= 256 i-blocks x 4 j-slices),
// 4 blocks/CU, 32 rows/block. adj DIRECT int32, plain loads (nt regressed, R5);
// loads at chunk top, consumed immediately; prefetch variants WORSE (R2).
// R7: fin fused -- the LAST of an i0-group's 4 slice-blocks (device-scope
// completion counter; no spin, no deadlock) merges the 4 partial sets and
// writes out with divide+ELU. Cross-XCD visibility: vmcnt-drain at barrier +
// __threadfence (L2 wb) before the atomic; __threadfence (inv) after winning.
__global__ __launch_bounds__(256) void gat_kernel(const int* __restrict__ adj,
                                                  const unsigned short* __restrict__ whB,
                                                  const float* __restrict__ s1p,
                                                  const float* __restrict__ s2p,
                                                  float* __restrict__ nums,    // 4 slices
                                                  float* __restrict__ dens,    // 4 x N
                                                  int* __restrict__ cnt,       // 256
                                                  float* __restrict__ out) {
    __shared__ __align__(16) unsigned short sP[MT][KC + 8];
    __shared__ __align__(16) float sS2[JW];       // slice-local 2048 cols, 8 KB
    __shared__ float sDen[MT];
    __shared__ float sS1[MT];
    __shared__ int sRank;
    const int t = threadIdx.x;
    const int slice = blockIdx.x & (JS - 1);
    const int i0 = (blockIdx.x >> 2) * MT;
    const int jb = slice * JW;
    const int kb0 = slice * (JW / 32);
    const size_t NF = (size_t)N_NODES * FOUT;
    float* __restrict__ num = nums + (size_t)slice * NF;
    float* __restrict__ den = dens + (size_t)slice * N_NODES;

    // ---- sum 4 s2 partials into sS2 (32 KB L2-hit reads, once per block) ----
    {
        const float* p0 = s2p + jb + t * 8;
        f32x4 a = {0.f, 0.f, 0.f, 0.f}, b = {0.f, 0.f, 0.f, 0.f};
#pragma unroll
        for (int pb = 0; pb < 4; ++pb) {
            a += *(const f32x4*)(p0 + (size_t)pb * N_NODES);
            b += *(const f32x4*)(p0 + (size_t)pb * N_NODES + 4);
        }
        *(f32x4*)&sS2[t * 8]     = a;
        *(f32x4*)&sS2[t * 8 + 4] = b;
    }
    if (t < MT) {
        float a = 0.f;
#pragma unroll
        for (int pb = 0; pb < 4; ++pb) a += s1p[(size_t)pb * N_NODES + i0 + t];
        sS1[t] = a;
        sDen[t] = 0.f;
    }
    __syncthreads();

    const int r0 = t >> 4;       // 0..15: P rows r0 and r0+16
    const int s  = t & 15;       // 16 consecutive cols [s*16, s*16+16)
    const int lane = t & 63;
    const int quad = lane >> 4;
    const int sl = lane & 15;
    const int wv = t >> 6;       // wave -> 32 features (fb pair wv*2, wv*2+1)
    const int* __restrict__ aRow0 = adj + (size_t)(i0 + r0) * N_NODES + jb;
    const int* __restrict__ aRow1 = aRow0 + (size_t)16 * N_NODES;
    const float s1a = sS1[r0];
    const float s1b = sS1[r0 + 16];

    f32x4 acc00 = {0.f,0.f,0.f,0.f}, acc01 = {0.f,0.f,0.f,0.f};
    f32x4 acc10 = {0.f,0.f,0.f,0.f}, acc11 = {0.f,0.f,0.f,0.f};

    for (int ch = 0; ch < NCHS; ++ch) {
        const int cb = ch * KC + s * 16;   // column base within slice
        // ---- this chunk's adj loads (coalesced 1 KB/16T) + s2 from LDS ----
        i32x4 av0[4], av1[4];
        f32x4 sv[4];
#pragma unroll
        for (int q = 0; q < 4; ++q) {
            av0[q] = *(const i32x4*)&aRow0[cb + q * 4];
            av1[q] = *(const i32x4*)&aRow1[cb + q * 4];
            sv[q]  = *(const f32x4*)&sS2[cb + q * 4];
        }
        // ---- build P tile (bf16, exp2 domain) + row-sum partials ----
        float part0 = 0.f, part1 = 0.f;
        unsigned int w0[8], w1[8];
#pragma unroll
        for (int q = 0; q < 4; ++q) {
            float p0[4], p1v[4];
#pragma unroll
            for (int r = 0; r < 4; ++r) {
                float y0 = s1a + sv[q][r];
                float y1 = s1b + sv[q][r];
                y0 = fmaxf(y0, 0.2f * y0);
                y1 = fmaxf(y1, 0.2f * y1);
                float e0 = __builtin_amdgcn_exp2f(y0);
                float e1 = __builtin_amdgcn_exp2f(y1);
                p0[r]  = (av0[q][r] > 0) ? e0 : 0.f;
                p1v[r] = (av1[q][r] > 0) ? e1 : 0.f;
                part0 += p0[r];
                part1 += p1v[r];
            }
            w0[2 * q]     = pack_bf16(p0[0], p0[1]);
            w0[2 * q + 1] = pack_bf16(p0[2], p0[3]);
            w1[2 * q]     = pack_bf16(p1v[0], p1v[1]);
            w1[2 * q + 1] = pack_bf16(p1v[2], p1v[3]);
        }
        // ---- stage P rows as 4x ds_write_b128 ----
        u32x4 ra = {w0[0], w0[1], w0[2], w0[3]};
        u32x4 rb = {w0[4], w0[5], w0[6], w0[7]};
        u32x4 rc = {w1[0], w1[1], w1[2], w1[3]};
        u32x4 rd = {w1[4], w1[5], w1[6], w1[7]};
        *(u32x4*)&sP[r0][s * 16]          = ra;
        *(u32x4*)&sP[r0][s * 16 + 8]      = rb;
        *(u32x4*)&sP[r0 + 16][s * 16]     = rc;
        *(u32x4*)&sP[r0 + 16][s * 16 + 8] = rd;
        // reduce partials across the 16 lanes sharing a row
        part0 += __shfl_xor(part0, 1); part1 += __shfl_xor(part1, 1);
        part0 += __shfl_xor(part0, 2); part1 += __shfl_xor(part1, 2);
        part0 += __shfl_xor(part0, 4); part1 += __shfl_xor(part1, 4);
        part0 += __shfl_xor(part0, 8); part1 += __shfl_xor(part1, 8);
        if (s == 0) { sDen[r0] += part0; sDen[r0 + 16] += part1; }
        __syncthreads();
        // ---- MFMA: NUM[32 x 128] += P[32 x 256] @ Wh[256 x 128] ----
#pragma unroll
        for (int kq = 0; kq < KC / 32; ++kq) {
            bf16x8 a0  = *(const bf16x8*)&sP[sl][kq * 32 + quad * 8];
            bf16x8 a1f = *(const bf16x8*)&sP[16 + sl][kq * 32 + quad * 8];
            int kb = kb0 + ch * (KC / 32) + kq;
            const unsigned short* t0 = whB + ((size_t)(kb * 8 + wv * 2) << 9) + lane * 8;
            bf16x8 b0 = *(const bf16x8*)t0;          // contiguous 1 KB per wave
            bf16x8 b1 = *(const bf16x8*)(t0 + 512);
            acc00 = __builtin_amdgcn_mfma_f32_16x16x32_bf16(a0,  b0, acc00, 0, 0, 0);
            acc01 = __builtin_amdgcn_mfma_f32_16x16x32_bf16(a0,  b1, acc01, 0, 0, 0);
            acc10 = __builtin_amdgcn_mfma_f32_16x16x32_bf16(a1f, b0, acc10, 0, 0, 0);
            acc11 = __builtin_amdgcn_mfma_f32_16x16x32_bf16(a1f, b1, acc11, 0, 0, 0);
        }
        __syncthreads();
    }
    // ---- publish this slice's raw partials ----
    if (t < MT) den[i0 + t] = sDen[t];
#pragma unroll
    for (int m = 0; m < 2; ++m) {
#pragma unroll
        for (int nn = 0; nn < 2; ++nn) {
            f32x4 a = (m == 0) ? (nn == 0 ? acc00 : acc01) : (nn == 0 ? acc10 : acc11);
#pragma unroll
            for (int r = 0; r < 4; ++r) {
                int row = m * 16 + quad * 4 + r;     // D row=(lane>>4)*4+reg, col=lane&15
                num[(size_t)(i0 + row) * FOUT + wv * 32 + nn * 16 + sl] = a[r];
            }
        }
    }
    // ---- completion counter: last of the 4 slice-blocks merges (fin fused) --
    __syncthreads();                    // barrier drains vmcnt -> stores complete
    if (t == 0) {
        __threadfence();                // L2 writeback: publish to device scope
        sRank = atomicAdd(&cnt[blockIdx.x >> 2], 1);
    }
    __syncthreads();
    if (sRank != 3) return;             // block-uniform: only the last proceeds
    __threadfence();                    // invalidate before reading peer slices
    if (t < MT) {
        float d0 = dens[i0 + t],               d1 = dens[N_NODES + i0 + t];
        float d2 = dens[2 * N_NODES + i0 + t], d3 = dens[3 * N_NODES + i0 + t];
        sDen[t] = fmaxf(((d0 + d1) + d2) + d3, 1e-30f);
    }
    __syncthreads();
#pragma unroll
    for (int m = 0; m < 2; ++m) {
#pragma unroll
        for (int nn = 0; nn < 2; ++nn) {
#pragma unroll
            for (int r = 0; r < 4; ++r) {
                int row = m * 16 + quad * 4 + r;
                size_t off = (size_t)(i0 + row) * FOUT + wv * 32 + nn * 16 + sl;
                float n0 = nums[off],          n1 = nums[NF + off];
                float n2 = nums[2 * NF + off], n3 = nums[3 * NF + off];
                float v = ((n0 + n1) + (n2 + n3)) / sDen[row];
                out[off] = (v > 0.f) ? v : expm1f(v);
            }
        }
    }
}

extern "C" void kernel_launch(void* const* d_in, const int* in_sizes, int n_in,
                              void* d_out, int out_size, void* d_ws, size_t ws_size,
                              hipStream_t stream) {
    const float* h   = (const float*)d_in[0];
    const int*   adj = (const int*)d_in[1];
    const float* W   = (const float*)d_in[2];
    const float* a1  = (const float*)d_in[3];
    const float* a2  = (const float*)d_in[4];

    // d_ws layout (ws is 1 GiB per the harness fill; we use ~21 MB):
    //   [0, 2MB)    whB (bf16, fragment-ordered)
    //   [3MB)       cnt (256 ints, zeroed by wh each launch)
    //   [4MB..)     s1p(4xN) | s2p(4xN) | dens(4xN) | nums(4 x N*FOUT)
    char* ws = (char*)d_ws;
    unsigned short* whB = (unsigned short*)ws;
    int* cnt    = (int*)(ws + (3u << 20));
    float* s1p  = (float*)(ws + (4u << 20));
    float* s2p  = s1p + 4 * N_NODES;
    float* dens = s2p + 4 * N_NODES;
    float* nums = dens + 4 * N_NODES;
    float* out  = (float*)d_out;

    wh_kernel<<<dim3(N_NODES / 64, FOUT / 32), 256, 0, stream>>>(h, W, a1, a2,
                                                                 whB, s1p, s2p, cnt);
    gat_kernel<<<dim3((N_NODES / MT) * JS), 256, 0, stream>>>(adj, whB, s1p, s2p,
                                                              nums, dens, cnt, out);
}

// Round 8
// 397.727 us; speedup vs baseline: 1.2204x; 1.2204x over previous
//
#include <hip/hip_runtime.h>
#include <cstdint>
#include <cstddef>

// Dtypes PROVEN fp32 (R2 bf16-read -> NaN; R4 fp32-read -> pass, absmax 0.0078).
#define N_NODES 8192
#define FIN 256
#define FOUT 128
#define MT 32                 // rows per block in gat kernel
#define KC 256                // j-chunk size
#define JS 4                  // j slices (partial softmax, merged in fin_kernel)
#define JW (N_NODES / JS)     // 2048 columns per slice
#define NCHS (JW / KC)        // 8 chunks per block
#define LOG2E 1.4426950408889634f

typedef __attribute__((ext_vector_type(8))) short bf16x8;
typedef __attribute__((ext_vector_type(4))) float f32x4;
typedef __attribute__((ext_vector_type(4))) int i32x4;
typedef __attribute__((ext_vector_type(2))) unsigned int u32x2;
typedef __attribute__((ext_vector_type(4))) unsigned int u32x4;

__device__ __forceinline__ float bf2f(unsigned short u) {
    union { unsigned int i; float f; } v; v.i = ((unsigned int)u) << 16; return v.f;
}
__device__ __forceinline__ unsigned short f2bf(float f) {
    union { float f; unsigned int i; } v; v.f = f;
    unsigned int r = (v.i + 0x7FFFu + ((v.i >> 16) & 1u)) >> 16;
    return (unsigned short)r;
}
__device__ __forceinline__ unsigned int pack_bf16(float a, float b) {
    return (unsigned)f2bf(a) | ((unsigned)f2bf(b) << 16);
}

// whB fragment-order layout: tile (kb, fb) holds Wh[j=kb*32+quad*8+e][f=fb*16+sl]
// at element ((kb*8+fb)*512 + (quad*16+sl)*8 + e) -> a wave's B-load is one
// contiguous 1 KB burst.
__device__ __forceinline__ size_t whb_idx(int j, int f) {
    return ((size_t)((j >> 5) * 8 + (f >> 4)) << 9) + (((j >> 3) & 3) << 7)
         + ((f & 15) << 3) + (j & 7);
}

// ---------------- Kernel A: whB = fragment-ordered bf16 (h @ W^T), MFMA -------
// R6 structure (proven -16 us): h staged f32x4-coalesced -> bf16 LDS (stride
// 264, conflict-free b128); W staged in fragment order. s-pass fused (R4):
// per-f0-block partials plain-stored (gat sums them).
__global__ __launch_bounds__(256) void wh_kernel(const float* __restrict__ h,
                                                 const float* __restrict__ W,
                                                 const float* __restrict__ a1,
                                                 const float* __restrict__ a2,
                                                 unsigned short* __restrict__ whB,
                                                 float* __restrict__ s1p,
                                                 float* __restrict__ s2p) {
    __shared__ __align__(16) unsigned short hB[64][264];       // 33 KB bf16
    __shared__ __align__(16) unsigned short wLds[16 * 64 * 8]; // 16 KB frag order
    const int t = threadIdx.x;
    const int i0 = blockIdx.x * 64;
    const int f0 = blockIdx.y * 32;
    // ---- stage h (64 x 256 f32, fully coalesced) -> bf16 LDS ----
#pragma unroll
    for (int c = 0; c < 8; ++c) {
        int chunk = c * 256 + t;          // 0..2047: 8-col groups
        int row = chunk >> 5;             // 0..63
        int g8  = chunk & 31;             // col group [g8*8, g8*8+8)
        const float* hp = &h[(size_t)(i0 + row) * FIN + g8 * 8];
        f32x4 v0 = *(const f32x4*)hp;
        f32x4 v1 = *(const f32x4*)(hp + 4);
        u32x4 pk;
        pk.x = pack_bf16(v0[0], v0[1]); pk.y = pack_bf16(v0[2], v0[3]);
        pk.z = pack_bf16(v1[0], v1[1]); pk.w = pack_bf16(v1[2], v1[3]);
        *(u32x4*)&hB[row][g8 * 8] = pk;
    }
    // ---- stage W tile (32 f x 256 k) -> bf16 fragment order (R5, proven) ----
    {
        const int kk = t & 7;          // k-tile this thread fills
        const int fr = t >> 3;         // local f row 0..31
        const int fh = fr >> 4;
        const float* wr = W + (size_t)(f0 + fr) * FIN + kk * 32;
#pragma unroll
        for (int g = 0; g < 4; ++g) {  // quad groups
            f32x4 v0 = *(const f32x4*)(wr + g * 8);
            f32x4 v1 = *(const f32x4*)(wr + g * 8 + 4);
            u32x4 pk;
            pk.x = pack_bf16(v0[0], v0[1]); pk.y = pack_bf16(v0[2], v0[3]);
            pk.z = pack_bf16(v1[0], v1[1]); pk.w = pack_bf16(v1[2], v1[3]);
            *(u32x4*)&wLds[(size_t)(((kk * 2 + fh) * 64) + (fr & 15) + g * 16) * 8] = pk;
        }
    }
    __syncthreads();
    const int lane = t & 63;
    const int wv = t >> 6;             // i-stripe: rows i0+wv*16 .. +15
    const int quad = lane >> 4;
    const int sl = lane & 15;
    f32x4 acc0 = {0.f,0.f,0.f,0.f}, acc1 = {0.f,0.f,0.f,0.f};
#pragma unroll
    for (int kk = 0; kk < 8; ++kk) {
        bf16x8 A  = *(const bf16x8*)&hB[wv * 16 + sl][kk * 32 + quad * 8];
        bf16x8 B0 = *(const bf16x8*)&wLds[(size_t)((kk * 2 + 0) * 64 + lane) * 8];
        bf16x8 B1 = *(const bf16x8*)&wLds[(size_t)((kk * 2 + 1) * 64 + lane) * 8];
        acc0 = __builtin_amdgcn_mfma_f32_16x16x32_bf16(A, B0, acc0, 0, 0, 0);
        acc1 = __builtin_amdgcn_mfma_f32_16x16x32_bf16(A, B1, acc1, 0, 0, 0);
    }
    // ---- D layout: i-local = wv*16 + quad*4 + r, f-local = fh*16 + sl ----
    const float a1v0 = a1[f0 + sl], a1v1 = a1[f0 + 16 + sl];
    const float a2v0 = a2[f0 + sl], a2v1 = a2[f0 + 16 + sl];
    float c1[4], c2[4];
#pragma unroll
    for (int r = 0; r < 4; ++r) {
        int i = i0 + wv * 16 + quad * 4 + r;
        whB[whb_idx(i, f0 + sl)]      = f2bf(acc0[r]);
        whB[whb_idx(i, f0 + 16 + sl)] = f2bf(acc1[r]);
        c1[r] = acc0[r] * a1v0 + acc1[r] * a1v1;
        c2[r] = acc0[r] * a2v0 + acc1[r] * a2v1;
    }
    // reduce the 16 sl-lanes (full 32-f partial lives in every quad group)
#pragma unroll
    for (int r = 0; r < 4; ++r) {
        c1[r] += __shfl_xor(c1[r], 1); c2[r] += __shfl_xor(c2[r], 1);
        c1[r] += __shfl_xor(c1[r], 2); c2[r] += __shfl_xor(c2[r], 2);
        c1[r] += __shfl_xor(c1[r], 4); c2[r] += __shfl_xor(c2[r], 4);
        c1[r] += __shfl_xor(c1[r], 8); c2[r] += __shfl_xor(c2[r], 8);
    }
    if (sl == 0) {
#pragma unroll
        for (int r = 0; r < 4; ++r) {
            int i = i0 + wv * 16 + quad * 4 + r;
            s1p[(size_t)blockIdx.y * N_NODES + i] = c1[r] * LOG2E;
            s2p[(size_t)blockIdx.y * N_NODES + i] = c2[r] * LOG2E;
        }
    }
}

// ---------------- Kernel C: fused mask+softmax-partial+PV MFMA ----------------
// R6 main loop + R8: DOUBLE-BUFFERED adj prefetch. R7 profile proved gat is
// LATENCY-bound (hbm 9% peak, Mfma 2.7%, VALU 10%, occ 27%), not BW-bound:
// adj loads were issued at chunk top and consumed immediately, exposing full
// L3/HBM latency once per chunk inside a barrier-locked phase. Now chunk ch+1's
// loads issue BEFORE P-build of ch (fully-unrolled, [ch&1] regs constant-fold)
// -> ~500+ cycles of P-build+shfl+barrier+MFMA cover the latency.
// VGPR 56 -> ~90 (R2's failed variant was capped at 128 w/ launch_bounds).
__global__ __launch_bounds__(256) void gat_kernel(const int* __restrict__ adj,
                                                  const unsigned short* __restrict__ whB,
                                                  const float* __restrict__ s1p,
                                                  const float* __restrict__ s2p,
                                                  float* __restrict__ out,     // slice-0 num
                                                  float* __restrict__ nums,    // slices 1..3
                                                  float* __restrict__ dens) {  // 4 x N
    __shared__ __align__(16) unsigned short sP[MT][KC + 8];
    __shared__ __align__(16) float sS2[JW];       // slice-local 2048 cols, 8 KB
    __shared__ float sDen[MT];
    __shared__ float sS1[MT];
    const int t = threadIdx.x;
    const int slice = blockIdx.x & (JS - 1);
    const int i0 = (blockIdx.x >> 2) * MT;
    const int jb = slice * JW;
    const int kb0 = slice * (JW / 32);
    float* __restrict__ num = slice ? (nums + (size_t)(slice - 1) * N_NODES * FOUT) : out;
    float* __restrict__ den = dens + (size_t)slice * N_NODES;

    // ---- sum 4 s2 partials into sS2 (32 KB L2-hit reads, once per block) ----
    {
        const float* p0 = s2p + jb + t * 8;
        f32x4 a = {0.f, 0.f, 0.f, 0.f}, b = {0.f, 0.f, 0.f, 0.f};
#pragma unroll
        for (int pb = 0; pb < 4; ++pb) {
            a += *(const f32x4*)(p0 + (size_t)pb * N_NODES);
            b += *(const f32x4*)(p0 + (size_t)pb * N_NODES + 4);
        }
        *(f32x4*)&sS2[t * 8]     = a;
        *(f32x4*)&sS2[t * 8 + 4] = b;
    }
    if (t < MT) {
        float a = 0.f;
#pragma unroll
        for (int pb = 0; pb < 4; ++pb) a += s1p[(size_t)pb * N_NODES + i0 + t];
        sS1[t] = a;
        sDen[t] = 0.f;
    }
    __syncthreads();

    const int r0 = t >> 4;       // 0..15: P rows r0 and r0+16
    const int s  = t & 15;       // 16 consecutive cols [s*16, s*16+16)
    const int lane = t & 63;
    const int quad = lane >> 4;
    const int sl = lane & 15;
    const int wv = t >> 6;       // wave -> 32 features (fb pair wv*2, wv*2+1)
    const int* __restrict__ aRow0 = adj + (size_t)(i0 + r0) * N_NODES + jb;
    const int* __restrict__ aRow1 = aRow0 + (size_t)16 * N_NODES;
    const float s1a = sS1[r0];
    const float s1b = sS1[r0 + 16];

    f32x4 acc00 = {0.f,0.f,0.f,0.f}, acc01 = {0.f,0.f,0.f,0.f};
    f32x4 acc10 = {0.f,0.f,0.f,0.f}, acc11 = {0.f,0.f,0.f,0.f};

    // ---- prefetch chunk 0's adj (double-buffer lives in registers) ----
    i32x4 av0[2][4], av1[2][4];
#pragma unroll
    for (int q = 0; q < 4; ++q) {
        av0[0][q] = *(const i32x4*)&aRow0[s * 16 + q * 4];
        av1[0][q] = *(const i32x4*)&aRow1[s * 16 + q * 4];
    }

#pragma unroll
    for (int ch = 0; ch < NCHS; ++ch) {
        const int cur = ch & 1;
        const int nxt = cur ^ 1;
        // ---- issue NEXT chunk's adj loads (hidden under P-build+MFMA) ----
        if (ch + 1 < NCHS) {
            const int cbn = (ch + 1) * KC + s * 16;
#pragma unroll
            for (int q = 0; q < 4; ++q) {
                av0[nxt][q] = *(const i32x4*)&aRow0[cbn + q * 4];
                av1[nxt][q] = *(const i32x4*)&aRow1[cbn + q * 4];
            }
        }
        const int cb = ch * KC + s * 16;   // column base within slice
        // ---- build P tile (bf16, exp2 domain) + row-sum partials ----
        float part0 = 0.f, part1 = 0.f;
        unsigned int w0[8], w1[8];
#pragma unroll
        for (int q = 0; q < 4; ++q) {
            f32x4 sv = *(const f32x4*)&sS2[cb + q * 4];
            float p0[4], p1v[4];
#pragma unroll
            for (int r = 0; r < 4; ++r) {
                float y0 = s1a + sv[r];
                float y1 = s1b + sv[r];
                y0 = fmaxf(y0, 0.2f * y0);
                y1 = fmaxf(y1, 0.2f * y1);
                float e0 = __builtin_amdgcn_exp2f(y0);
                float e1 = __builtin_amdgcn_exp2f(y1);
                p0[r]  = (av0[cur][q][r] > 0) ? e0 : 0.f;
                p1v[r] = (av1[cur][q][r] > 0) ? e1 : 0.f;
                part0 += p0[r];
                part1 += p1v[r];
            }
            w0[2 * q]     = pack_bf16(p0[0], p0[1]);
            w0[2 * q + 1] = pack_bf16(p0[2], p0[3]);
            w1[2 * q]     = pack_bf16(p1v[0], p1v[1]);
            w1[2 * q + 1] = pack_bf16(p1v[2], p1v[3]);
        }
        // ---- stage P rows as 4x ds_write_b128 ----
        u32x4 ra = {w0[0], w0[1], w0[2], w0[3]};
        u32x4 rb = {w0[4], w0[5], w0[6], w0[7]};
        u32x4 rc = {w1[0], w1[1], w1[2], w1[3]};
        u32x4 rd = {w1[4], w1[5], w1[6], w1[7]};
        *(u32x4*)&sP[r0][s * 16]          = ra;
        *(u32x4*)&sP[r0][s * 16 + 8]      = rb;
        *(u32x4*)&sP[r0 + 16][s * 16]     = rc;
        *(u32x4*)&sP[r0 + 16][s * 16 + 8] = rd;
        // reduce partials across the 16 lanes sharing a row
        part0 += __shfl_xor(part0, 1); part1 += __shfl_xor(part1, 1);
        part0 += __shfl_xor(part0, 2); part1 += __shfl_xor(part1, 2);
        part0 += __shfl_xor(part0, 4); part1 += __shfl_xor(part1, 4);
        part0 += __shfl_xor(part0, 8); part1 += __shfl_xor(part1, 8);
        if (s == 0) { sDen[r0] += part0; sDen[r0 + 16] += part1; }
        __syncthreads();
        // ---- MFMA: NUM[32 x 128] += P[32 x 256] @ Wh[256 x 128] ----
#pragma unroll
        for (int kq = 0; kq < KC / 32; ++kq) {
            bf16x8 a0  = *(const bf16x8*)&sP[sl][kq * 32 + quad * 8];
            bf16x8 a1f = *(const bf16x8*)&sP[16 + sl][kq * 32 + quad * 8];
            int kb = kb0 + ch * (KC / 32) + kq;
            const unsigned short* t0 = whB + ((size_t)(kb * 8 + wv * 2) << 9) + lane * 8;
            bf16x8 b0 = *(const bf16x8*)t0;          // contiguous 1 KB per wave
            bf16x8 b1 = *(const bf16x8*)(t0 + 512);
            acc00 = __builtin_amdgcn_mfma_f32_16x16x32_bf16(a0,  b0, acc00, 0, 0, 0);
            acc01 = __builtin_amdgcn_mfma_f32_16x16x32_bf16(a0,  b1, acc01, 0, 0, 0);
            acc10 = __builtin_amdgcn_mfma_f32_16x16x32_bf16(a1f, b0, acc10, 0, 0, 0);
            acc11 = __builtin_amdgcn_mfma_f32_16x16x32_bf16(a1f, b1, acc11, 0, 0, 0);
        }
        __syncthreads();
    }
    // ---- epilogue: raw partials (divide + ELU in fin_kernel) ----
    if (t < MT) den[i0 + t] = sDen[t];
#pragma unroll
    for (int m = 0; m < 2; ++m) {
#pragma unroll
        for (int nn = 0; nn < 2; ++nn) {
            f32x4 a = (m == 0) ? (nn == 0 ? acc00 : acc01) : (nn == 0 ? acc10 : acc11);
#pragma unroll
            for (int r = 0; r < 4; ++r) {
                int row = m * 16 + quad * 4 + r;     // D row=(lane>>4)*4+reg, col=lane&15
                num[(size_t)(i0 + row) * FOUT + wv * 32 + nn * 16 + sl] = a[r];
            }
        }
    }
}

// ---------------- Kernel D: merge 4 slices, divide, ELU (in-place, x4 vec) ----
__global__ __launch_bounds__(256) void fin_kernel(float* __restrict__ out,      // = num0
                                                  const float* __restrict__ nums,
                                                  const float* __restrict__ dens) {
    const int idx4 = blockIdx.x * 256 + threadIdx.x;   // grid 1024
    const int idx = idx4 * 4;
    const int i = idx >> 7;                            // FOUT = 128 (4 | 128)
    const size_t NF = (size_t)N_NODES * FOUT;
    f32x4 n0 = *(f32x4*)&out[idx];
    f32x4 n1 = *(const f32x4*)&nums[idx];
    f32x4 n2 = *(const f32x4*)&nums[NF + idx];
    f32x4 n3 = *(const f32x4*)&nums[2 * NF + idx];
    float denv = dens[i] + dens[N_NODES + i] + dens[2 * N_NODES + i] + dens[3 * N_NODES + i];
    float dv = fmaxf(denv, 1e-30f);
    f32x4 r;
#pragma unroll
    for (int k = 0; k < 4; ++k) {
        float numv = (n0[k] + n1[k]) + (n2[k] + n3[k]);
        float v = numv / dv;                           // exact div (bit-compat)
        r[k] = (v > 0.f) ? v : expm1f(v);
    }
    *(f32x4*)&out[idx] = r;
}

extern "C" void kernel_launch(void* const* d_in, const int* in_sizes, int n_in,
                              void* d_out, int out_size, void* d_ws, size_t ws_size,
                              hipStream_t stream) {
    const float* h   = (const float*)d_in[0];
    const int*   adj = (const int*)d_in[1];
    const float* W   = (const float*)d_in[2];
    const float* a1  = (const float*)d_in[3];
    const float* a2  = (const float*)d_in[4];

    // d_ws layout (ws is 1 GiB per the harness fill; we use ~17 MB):
    //   [0, 2MB)    whB (bf16, fragment-ordered)
    //   [4MB..)     s1p(4xN) | s2p(4xN) | dens(4xN) | nums(3 x N*FOUT)
    char* ws = (char*)d_ws;
    unsigned short* whB = (unsigned short*)ws;
    float* s1p  = (float*)(ws + (4u << 20));
    float* s2p  = s1p + 4 * N_NODES;
    float* dens = s2p + 4 * N_NODES;
    float* nums = dens + 4 * N_NODES;
    float* out  = (float*)d_out;

    wh_kernel<<<dim3(N_NODES / 64, FOUT / 32), 256, 0, stream>>>(h, W, a1, a2,
                                                                 whB, s1p, s2p);
    gat_kernel<<<dim3((N_NODES / MT) * JS), 256, 0, stream>>>(adj, whB, s1p, s2p,
                                                              out, nums, dens);
    fin_kernel<<<dim3(N_NODES * FOUT / 1024), 256, 0, stream>>>(out, nums, dens);
}

// Round 9
// 381.892 us; speedup vs baseline: 1.2710x; 1.0415x over previous
//
#include <hip/hip_runtime.h>
#include <cstdint>
#include <cstddef>

// Dtypes PROVEN fp32 (R2 bf16-read -> NaN; R4 fp32-read -> pass, absmax 0.0078).
#define N_NODES 8192
#define FIN 256
#define FOUT 128
#define MT 32                 // rows per block in gat kernel
#define KC 256                // j-chunk size
#define JS 4                  // j slices (partial softmax, merged in fin_kernel)
#define JW (N_NODES / JS)     // 2048 columns per slice
#define NCHS (JW / KC)        // 8 chunks per block
#define LOG2E 1.4426950408889634f

typedef __attribute__((ext_vector_type(8))) short bf16x8;
typedef __attribute__((ext_vector_type(4))) float f32x4;
typedef __attribute__((ext_vector_type(4))) int i32x4;
typedef __attribute__((ext_vector_type(2))) unsigned int u32x2;
typedef __attribute__((ext_vector_type(4))) unsigned int u32x4;

__device__ __forceinline__ float bf2f(unsigned short u) {
    union { unsigned int i; float f; } v; v.i = ((unsigned int)u) << 16; return v.f;
}
__device__ __forceinline__ unsigned short f2bf(float f) {
    union { float f; unsigned int i; } v; v.f = f;
    unsigned int r = (v.i + 0x7FFFu + ((v.i >> 16) & 1u)) >> 16;
    return (unsigned short)r;
}
__device__ __forceinline__ unsigned int pack_bf16(float a, float b) {
    return (unsigned)f2bf(a) | ((unsigned)f2bf(b) << 16);
}

// whB fragment-order layout: tile (kb, fb) holds Wh[j=kb*32+quad*8+e][f=fb*16+sl]
// at element ((kb*8+fb)*512 + (quad*16+sl)*8 + e) -> a wave's B-load is one
// contiguous 1 KB burst.
__device__ __forceinline__ size_t whb_idx(int j, int f) {
    return ((size_t)((j >> 5) * 8 + (f >> 4)) << 9) + (((j >> 3) & 3) << 7)
         + ((f & 15) << 3) + (j & 7);
}

// ---------------- Kernel A: whB = fragment-ordered bf16 (h @ W^T), MFMA -------
// R6 structure (proven -16 us): h staged f32x4-coalesced -> bf16 LDS (stride
// 264, conflict-free b128); W staged in fragment order. s-pass fused (R4):
// per-f0-block partials plain-stored (gat sums them).
__global__ __launch_bounds__(256) void wh_kernel(const float* __restrict__ h,
                                                 const float* __restrict__ W,
                                                 const float* __restrict__ a1,
                                                 const float* __restrict__ a2,
                                                 unsigned short* __restrict__ whB,
                                                 float* __restrict__ s1p,
                                                 float* __restrict__ s2p) {
    __shared__ __align__(16) unsigned short hB[64][264];       // 33 KB bf16
    __shared__ __align__(16) unsigned short wLds[16 * 64 * 8]; // 16 KB frag order
    const int t = threadIdx.x;
    const int i0 = blockIdx.x * 64;
    const int f0 = blockIdx.y * 32;
    // ---- stage h (64 x 256 f32, fully coalesced) -> bf16 LDS ----
#pragma unroll
    for (int c = 0; c < 8; ++c) {
        int chunk = c * 256 + t;          // 0..2047: 8-col groups
        int row = chunk >> 5;             // 0..63
        int g8  = chunk & 31;             // col group [g8*8, g8*8+8)
        const float* hp = &h[(size_t)(i0 + row) * FIN + g8 * 8];
        f32x4 v0 = *(const f32x4*)hp;
        f32x4 v1 = *(const f32x4*)(hp + 4);
        u32x4 pk;
        pk.x = pack_bf16(v0[0], v0[1]); pk.y = pack_bf16(v0[2], v0[3]);
        pk.z = pack_bf16(v1[0], v1[1]); pk.w = pack_bf16(v1[2], v1[3]);
        *(u32x4*)&hB[row][g8 * 8] = pk;
    }
    // ---- stage W tile (32 f x 256 k) -> bf16 fragment order (R5, proven) ----
    {
        const int kk = t & 7;          // k-tile this thread fills
        const int fr = t >> 3;         // local f row 0..31
        const int fh = fr >> 4;
        const float* wr = W + (size_t)(f0 + fr) * FIN + kk * 32;
#pragma unroll
        for (int g = 0; g < 4; ++g) {  // quad groups
            f32x4 v0 = *(const f32x4*)(wr + g * 8);
            f32x4 v1 = *(const f32x4*)(wr + g * 8 + 4);
            u32x4 pk;
            pk.x = pack_bf16(v0[0], v0[1]); pk.y = pack_bf16(v0[2], v0[3]);
            pk.z = pack_bf16(v1[0], v1[1]); pk.w = pack_bf16(v1[2], v1[3]);
            *(u32x4*)&wLds[(size_t)(((kk * 2 + fh) * 64) + (fr & 15) + g * 16) * 8] = pk;
        }
    }
    __syncthreads();
    const int lane = t & 63;
    const int wv = t >> 6;             // i-stripe: rows i0+wv*16 .. +15
    const int quad = lane >> 4;
    const int sl = lane & 15;
    f32x4 acc0 = {0.f,0.f,0.f,0.f}, acc1 = {0.f,0.f,0.f,0.f};
#pragma unroll
    for (int kk = 0; kk < 8; ++kk) {
        bf16x8 A  = *(const bf16x8*)&hB[wv * 16 + sl][kk * 32 + quad * 8];
        bf16x8 B0 = *(const bf16x8*)&wLds[(size_t)((kk * 2 + 0) * 64 + lane) * 8];
        bf16x8 B1 = *(const bf16x8*)&wLds[(size_t)((kk * 2 + 1) * 64 + lane) * 8];
        acc0 = __builtin_amdgcn_mfma_f32_16x16x32_bf16(A, B0, acc0, 0, 0, 0);
        acc1 = __builtin_amdgcn_mfma_f32_16x16x32_bf16(A, B1, acc1, 0, 0, 0);
    }
    // ---- D layout: i-local = wv*16 + quad*4 + r, f-local = fh*16 + sl ----
    const float a1v0 = a1[f0 + sl], a1v1 = a1[f0 + 16 + sl];
    const float a2v0 = a2[f0 + sl], a2v1 = a2[f0 + 16 + sl];
    float c1[4], c2[4];
#pragma unroll
    for (int r = 0; r < 4; ++r) {
        int i = i0 + wv * 16 + quad * 4 + r;
        whB[whb_idx(i, f0 + sl)]      = f2bf(acc0[r]);
        whB[whb_idx(i, f0 + 16 + sl)] = f2bf(acc1[r]);
        c1[r] = acc0[r] * a1v0 + acc1[r] * a1v1;
        c2[r] = acc0[r] * a2v0 + acc1[r] * a2v1;
    }
    // reduce the 16 sl-lanes (full 32-f partial lives in every quad group)
#pragma unroll
    for (int r = 0; r < 4; ++r) {
        c1[r] += __shfl_xor(c1[r], 1); c2[r] += __shfl_xor(c2[r], 1);
        c1[r] += __shfl_xor(c1[r], 2); c2[r] += __shfl_xor(c2[r], 2);
        c1[r] += __shfl_xor(c1[r], 4); c2[r] += __shfl_xor(c2[r], 4);
        c1[r] += __shfl_xor(c1[r], 8); c2[r] += __shfl_xor(c2[r], 8);
    }
    if (sl == 0) {
#pragma unroll
        for (int r = 0; r < 4; ++r) {
            int i = i0 + wv * 16 + quad * 4 + r;
            s1p[(size_t)blockIdx.y * N_NODES + i] = c1[r] * LOG2E;
            s2p[(size_t)blockIdx.y * N_NODES + i] = c2[r] * LOG2E;
        }
    }
}

// ---------------- Kernel C: fused mask+softmax-partial+PV MFMA ----------------
// EXACT R4/R6 structure (champion, 383.2 us). grid 1024 (= 256 i-blocks x 4
// j-slices), 32 rows/block. adj DIRECT int32, plain loads at chunk top,
// consumed immediately. PROVEN DEAD ENDS: nt-hints (R5 +), reg-prefetch
// dbuf (R8 +14.5: compiler vmcnt drain covers just-issued next-chunk loads),
// thread-remap+prefetch (R2 +11), fin-fusion w/ threadfence (R7 +102).
// s2 partials summed ONCE into LDS at block start (ds_read per chunk).
__global__ __launch_bounds__(256) void gat_kernel(const int* __restrict__ adj,
                                                  const unsigned short* __restrict__ whB,
                                                  const float* __restrict__ s1p,
                                                  const float* __restrict__ s2p,
                                                  float* __restrict__ out,     // slice-0 num
                                                  float* __restrict__ nums,    // slices 1..3
                                                  float* __restrict__ dens) {  // 4 x N
    __shared__ __align__(16) unsigned short sP[MT][KC + 8];
    __shared__ __align__(16) float sS2[JW];       // slice-local 2048 cols, 8 KB
    __shared__ float sDen[MT];
    __shared__ float sS1[MT];
    const int t = threadIdx.x;
    const int slice = blockIdx.x & (JS - 1);
    const int i0 = (blockIdx.x >> 2) * MT;
    const int jb = slice * JW;
    const int kb0 = slice * (JW / 32);
    float* __restrict__ num = slice ? (nums + (size_t)(slice - 1) * N_NODES * FOUT) : out;
    float* __restrict__ den = dens + (size_t)slice * N_NODES;

    // ---- sum 4 s2 partials into sS2 (32 KB L2-hit reads, once per block) ----
    {
        const float* p0 = s2p + jb + t * 8;
        f32x4 a = {0.f, 0.f, 0.f, 0.f}, b = {0.f, 0.f, 0.f, 0.f};
#pragma unroll
        for (int pb = 0; pb < 4; ++pb) {
            a += *(const f32x4*)(p0 + (size_t)pb * N_NODES);
            b += *(const f32x4*)(p0 + (size_t)pb * N_NODES + 4);
        }
        *(f32x4*)&sS2[t * 8]     = a;
        *(f32x4*)&sS2[t * 8 + 4] = b;
    }
    if (t < MT) {
        float a = 0.f;
#pragma unroll
        for (int pb = 0; pb < 4; ++pb) a += s1p[(size_t)pb * N_NODES + i0 + t];
        sS1[t] = a;
        sDen[t] = 0.f;
    }
    __syncthreads();

    const int r0 = t >> 4;       // 0..15: P rows r0 and r0+16
    const int s  = t & 15;       // 16 consecutive cols [s*16, s*16+16)
    const int lane = t & 63;
    const int quad = lane >> 4;
    const int sl = lane & 15;
    const int wv = t >> 6;       // wave -> 32 features (fb pair wv*2, wv*2+1)
    const int* __restrict__ aRow0 = adj + (size_t)(i0 + r0) * N_NODES + jb;
    const int* __restrict__ aRow1 = aRow0 + (size_t)16 * N_NODES;
    const float s1a = sS1[r0];
    const float s1b = sS1[r0 + 16];

    f32x4 acc00 = {0.f,0.f,0.f,0.f}, acc01 = {0.f,0.f,0.f,0.f};
    f32x4 acc10 = {0.f,0.f,0.f,0.f}, acc11 = {0.f,0.f,0.f,0.f};

    for (int ch = 0; ch < NCHS; ++ch) {
        const int cb = ch * KC + s * 16;   // column base within slice
        // ---- this chunk's adj loads (coalesced 1 KB/16T) + s2 from LDS ----
        i32x4 av0[4], av1[4];
        f32x4 sv[4];
#pragma unroll
        for (int q = 0; q < 4; ++q) {
            av0[q] = *(const i32x4*)&aRow0[cb + q * 4];
            av1[q] = *(const i32x4*)&aRow1[cb + q * 4];
            sv[q]  = *(const f32x4*)&sS2[cb + q * 4];
        }
        // ---- build P tile (bf16, exp2 domain) + row-sum partials ----
        float part0 = 0.f, part1 = 0.f;
        unsigned int w0[8], w1[8];
#pragma unroll
        for (int q = 0; q < 4; ++q) {
            float p0[4], p1v[4];
#pragma unroll
            for (int r = 0; r < 4; ++r) {
                float y0 = s1a + sv[q][r];
                float y1 = s1b + sv[q][r];
                y0 = fmaxf(y0, 0.2f * y0);
                y1 = fmaxf(y1, 0.2f * y1);
                float e0 = __builtin_amdgcn_exp2f(y0);
                float e1 = __builtin_amdgcn_exp2f(y1);
                p0[r]  = (av0[q][r] > 0) ? e0 : 0.f;
                p1v[r] = (av1[q][r] > 0) ? e1 : 0.f;
                part0 += p0[r];
                part1 += p1v[r];
            }
            w0[2 * q]     = pack_bf16(p0[0], p0[1]);
            w0[2 * q + 1] = pack_bf16(p0[2], p0[3]);
            w1[2 * q]     = pack_bf16(p1v[0], p1v[1]);
            w1[2 * q + 1] = pack_bf16(p1v[2], p1v[3]);
        }
        // ---- stage P rows as 4x ds_write_b128 ----
        u32x4 ra = {w0[0], w0[1], w0[2], w0[3]};
        u32x4 rb = {w0[4], w0[5], w0[6], w0[7]};
        u32x4 rc = {w1[0], w1[1], w1[2], w1[3]};
        u32x4 rd = {w1[4], w1[5], w1[6], w1[7]};
        *(u32x4*)&sP[r0][s * 16]          = ra;
        *(u32x4*)&sP[r0][s * 16 + 8]      = rb;
        *(u32x4*)&sP[r0 + 16][s * 16]     = rc;
        *(u32x4*)&sP[r0 + 16][s * 16 + 8] = rd;
        // reduce partials across the 16 lanes sharing a row
        part0 += __shfl_xor(part0, 1); part1 += __shfl_xor(part1, 1);
        part0 += __shfl_xor(part0, 2); part1 += __shfl_xor(part1, 2);
        part0 += __shfl_xor(part0, 4); part1 += __shfl_xor(part1, 4);
        part0 += __shfl_xor(part0, 8); part1 += __shfl_xor(part1, 8);
        if (s == 0) { sDen[r0] += part0; sDen[r0 + 16] += part1; }
        __syncthreads();
        // ---- MFMA: NUM[32 x 128] += P[32 x 256] @ Wh[256 x 128] ----
#pragma unroll
        for (int kq = 0; kq < KC / 32; ++kq) {
            bf16x8 a0  = *(const bf16x8*)&sP[sl][kq * 32 + quad * 8];
            bf16x8 a1f = *(const bf16x8*)&sP[16 + sl][kq * 32 + quad * 8];
            int kb = kb0 + ch * (KC / 32) + kq;
            const unsigned short* t0 = whB + ((size_t)(kb * 8 + wv * 2) << 9) + lane * 8;
            bf16x8 b0 = *(const bf16x8*)t0;          // contiguous 1 KB per wave
            bf16x8 b1 = *(const bf16x8*)(t0 + 512);
            acc00 = __builtin_amdgcn_mfma_f32_16x16x32_bf16(a0,  b0, acc00, 0, 0, 0);
            acc01 = __builtin_amdgcn_mfma_f32_16x16x32_bf16(a0,  b1, acc01, 0, 0, 0);
            acc10 = __builtin_amdgcn_mfma_f32_16x16x32_bf16(a1f, b0, acc10, 0, 0, 0);
            acc11 = __builtin_amdgcn_mfma_f32_16x16x32_bf16(a1f, b1, acc11, 0, 0, 0);
        }
        __syncthreads();
    }
    // ---- epilogue: raw partials (divide + ELU in fin_kernel) ----
    if (t < MT) den[i0 + t] = sDen[t];
#pragma unroll
    for (int m = 0; m < 2; ++m) {
#pragma unroll
        for (int nn = 0; nn < 2; ++nn) {
            f32x4 a = (m == 0) ? (nn == 0 ? acc00 : acc01) : (nn == 0 ? acc10 : acc11);
#pragma unroll
            for (int r = 0; r < 4; ++r) {
                int row = m * 16 + quad * 4 + r;     // D row=(lane>>4)*4+reg, col=lane&15
                num[(size_t)(i0 + row) * FOUT + wv * 32 + nn * 16 + sl] = a[r];
            }
        }
    }
}

// ---------------- Kernel D: merge 4 slices, divide, ELU (in-place, x4 vec) ----
__global__ __launch_bounds__(256) void fin_kernel(float* __restrict__ out,      // = num0
                                                  const float* __restrict__ nums,
                                                  const float* __restrict__ dens) {
    const int idx4 = blockIdx.x * 256 + threadIdx.x;   // grid 1024
    const int idx = idx4 * 4;
    const int i = idx >> 7;                            // FOUT = 128 (4 | 128)
    const size_t NF = (size_t)N_NODES * FOUT;
    f32x4 n0 = *(f32x4*)&out[idx];
    f32x4 n1 = *(const f32x4*)&nums[idx];
    f32x4 n2 = *(const f32x4*)&nums[NF + idx];
    f32x4 n3 = *(const f32x4*)&nums[2 * NF + idx];
    float denv = dens[i] + dens[N_NODES + i] + dens[2 * N_NODES + i] + dens[3 * N_NODES + i];
    float dv = fmaxf(denv, 1e-30f);
    f32x4 r;
#pragma unroll
    for (int k = 0; k < 4; ++k) {
        float numv = (n0[k] + n1[k]) + (n2[k] + n3[k]);
        float v = numv / dv;                           // exact div (bit-compat)
        r[k] = (v > 0.f) ? v : expm1f(v);
    }
    *(f32x4*)&out[idx] = r;
}

extern "C" void kernel_launch(void* const* d_in, const int* in_sizes, int n_in,
                              void* d_out, int out_size, void* d_ws, size_t ws_size,
                              hipStream_t stream) {
    const float* h   = (const float*)d_in[0];
    const int*   adj = (const int*)d_in[1];
    const float* W   = (const float*)d_in[2];
    const float* a1  = (const float*)d_in[3];
    const float* a2  = (const float*)d_in[4];

    // d_ws layout (ws is 1 GiB per the harness fill; we use ~17 MB):
    //   [0, 2MB)    whB (bf16, fragment-ordered)
    //   [4MB..)     s1p(4xN) | s2p(4xN) | dens(4xN) | nums(3 x N*FOUT)
    char* ws = (char*)d_ws;
    unsigned short* whB = (unsigned short*)ws;
    float* s1p  = (float*)(ws + (4u << 20));
    float* s2p  = s1p + 4 * N_NODES;
    float* dens = s2p + 4 * N_NODES;
    float* nums = dens + 4 * N_NODES;
    float* out  = (float*)d_out;

    wh_kernel<<<dim3(N_NODES / 64, FOUT / 32), 256, 0, stream>>>(h, W, a1, a2,
                                                                 whB, s1p, s2p);
    gat_kernel<<<dim3((N_NODES / MT) * JS), 256, 0, stream>>>(adj, whB, s1p, s2p,
                                                              out, nums, dens);
    fin_kernel<<<dim3(N_NODES * FOUT / 1024), 256, 0, stream>>>(out, nums, dens);
}